// Round 2
// baseline (1634.208 us; speedup 1.0000x reference)
//
#include <hip/hip_runtime.h>
#include <cstddef>

typedef _Float16 h8 __attribute__((ext_vector_type(8)));
typedef _Float16 h4 __attribute__((ext_vector_type(4)));
typedef float f32x4 __attribute__((ext_vector_type(4)));

#define B_DIM 1024
#define T_DIM 1024
#define E_DIM 128
#define SW 136   // Wt LDS row stride in f16 elems; 272B rows -> 16B-aligned b128 reads, 2-way banks (free)

// tanh(x) = 1 - 2/(exp2(2x*log2e)+1); exact at both saturations, ~1e-6 abs err.
__device__ __forceinline__ float tanh_fast(float x) {
  float ex = __expf(2.0f * x);                  // v_mul + v_exp (exp2-based)
  return 1.0f - 2.0f * __builtin_amdgcn_rcpf(ex + 1.0f);
}

// Pre-kernel: vT[e][t] = (f16) v[t][e]  (128 x 1024 f16 = 256 KB in ws)
__global__ void v_transpose_kernel(const float* __restrict__ vp, _Float16* __restrict__ vT) {
  const int e = blockIdx.x;      // 0..127
  const int t = threadIdx.x;     // 0..255
  #pragma unroll
  for (int k = 0; k < 4; ++k)
    vT[e * 1024 + t + 256 * k] = (_Float16)vp[(t + 256 * k) * E_DIM + e];
}

// One WAVE (64 threads) per batch. 1024 blocks = 1 wave/SIMD device-wide.
// Barrier-free main loop: per 16-row t-slab,
//   step1: u = tanh(m_slab @ W_b + bias)  via mfma 16x16x32 f16 (K=128), C-layout regs
//   step2: pre^T += u^T @ v_slab          via mfma 16x16x16 f16 (K=16);
//          step1's C-layout (row=4q+r,col=l15) IS the A-layout (m=l15,k=4q+j) of D^T.
// Epilogue: softmax over m' per e-column + out = s^T alpha, all in regs/shuffles.
template <bool USE_VT>
__global__ __launch_bounds__(64, 1)
void attn_mv_main(const float* __restrict__ mp, const float* __restrict__ vp,
                  const _Float16* __restrict__ vTp, const float* __restrict__ Wp,
                  const float* __restrict__ bp, float* __restrict__ outp)
{
  const int bi   = blockIdx.x;
  const int lane = threadIdx.x;   // 0..63
  const int l15  = lane & 15;
  const int q    = lane >> 4;

  __shared__ _Float16 Wt[E_DIM * SW];   // W^T[f][e], f16, ~34.8 KB
  __shared__ float s_fin[E_DIM];

  // ---- stage W_b transposed to f16 (coalesced float4 reads; once per block)
  const float* Wb = Wp + (size_t)bi * (E_DIM * E_DIM);
  for (int i = lane; i < 4096; i += 64) {
    const int e  = i >> 5;
    const int f4 = (i & 31) << 2;
    f32x4 w = *(const f32x4*)&Wb[(e << 7) + f4];
    Wt[(f4 + 0) * SW + e] = (_Float16)w[0];
    Wt[(f4 + 1) * SW + e] = (_Float16)w[1];
    Wt[(f4 + 2) * SW + e] = (_Float16)w[2];
    Wt[(f4 + 3) * SW + e] = (_Float16)w[3];
  }
  __syncthreads();

  // pre^T accumulators: acc[mt][nt] covers m' = 16mt+4q+r, e = 16nt+l15
  f32x4 acc[8][8];
  #pragma unroll
  for (int mt = 0; mt < 8; ++mt)
    #pragma unroll
    for (int nt = 0; nt < 8; ++nt)
      #pragma unroll
      for (int r = 0; r < 4; ++r) acc[mt][nt][r] = 0.0f;

  // exact fp32 column sums of m: lane covers e = 32kk + 8q + j (summed over l15 later)
  float s_acc[4][8];
  #pragma unroll
  for (int kk = 0; kk < 4; ++kk)
    #pragma unroll
    for (int j = 0; j < 8; ++j) s_acc[kk][j] = 0.0f;

  const float* mblk = mp + (size_t)bi * T_DIM * E_DIM;

  #pragma unroll 1
  for (int it = 0; it < 64; ++it) {
    const int t0 = it << 4;

    // ---- m row load (lane owns row t0+l15; 32 floats), colsum + cvt to A-frags
    const float* mr = mblk + (size_t)(t0 + l15) * E_DIM;
    h8 ma[4];
    #pragma unroll
    for (int kk = 0; kk < 4; ++kk) {
      f32x4 lo = *(const f32x4*)&mr[32 * kk + 8 * q];
      f32x4 hi = *(const f32x4*)&mr[32 * kk + 8 * q + 4];
      #pragma unroll
      for (int j = 0; j < 4; ++j) {
        s_acc[kk][j]     += lo[j];
        s_acc[kk][4 + j] += hi[j];
        ma[kk][j]     = (_Float16)lo[j];
        ma[kk][4 + j] = (_Float16)hi[j];
      }
    }

    // ---- v B-frags for step2: B[k=4q+j][n=l15] = v[t0+4q+j][e=16nt+l15]
    h4 vb[8];
    if (USE_VT) {
      #pragma unroll
      for (int nt = 0; nt < 8; ++nt)
        vb[nt] = *(const h4*)&vTp[(16 * nt + l15) * 1024 + t0 + 4 * q];
    } else {
      #pragma unroll
      for (int nt = 0; nt < 8; ++nt)
        #pragma unroll
        for (int j = 0; j < 4; ++j)
          vb[nt][j] = (_Float16)vp[(t0 + 4 * q + j) * E_DIM + 16 * nt + l15];
    }

    // ---- bias prefetch (u row 4q+r -> global t = t0+4q+r; f = 16mt+l15)
    float bv[8][4];
    #pragma unroll
    for (int mt = 0; mt < 8; ++mt)
      #pragma unroll
      for (int r = 0; r < 4; ++r)
        bv[mt][r] = bp[(t0 + 4 * q + r) * E_DIM + 16 * mt + l15];

    // ---- step1: u slab (16 t-rows x 128 f), K=128 over e
    f32x4 uacc[8];
    #pragma unroll
    for (int mt = 0; mt < 8; ++mt)
      #pragma unroll
      for (int r = 0; r < 4; ++r) uacc[mt][r] = 0.0f;

    #pragma unroll
    for (int kk = 0; kk < 4; ++kk) {
      #pragma unroll
      for (int mt = 0; mt < 8; ++mt) {
        h8 bw = *(const h8*)&Wt[(16 * mt + l15) * SW + 32 * kk + 8 * q];
        uacc[mt] = __builtin_amdgcn_mfma_f32_16x16x32_f16(ma[kk], bw, uacc[mt], 0, 0, 0);
      }
    }

    // ---- tanh + pack: C-layout regs become A-frags of u^T directly
    h4 ufrag[8];
    #pragma unroll
    for (int mt = 0; mt < 8; ++mt)
      #pragma unroll
      for (int r = 0; r < 4; ++r)
        ufrag[mt][r] = (_Float16)tanh_fast(uacc[mt][r] + bv[mt][r]);

    // ---- step2: pre^T += u^T @ v, K=16, no LDS, no barrier
    #pragma unroll
    for (int mt = 0; mt < 8; ++mt)
      #pragma unroll
      for (int nt = 0; nt < 8; ++nt)
        acc[mt][nt] = __builtin_amdgcn_mfma_f32_16x16x16f16(ufrag[mt], vb[nt], acc[mt][nt], 0, 0, 0);
  }

  // ==== epilogue (single wave; shuffles + 128 floats of LDS) ====
  // finalize colsums s[e]: reduce over l15 (16 t-row owners)
  #pragma unroll
  for (int kk = 0; kk < 4; ++kk)
    #pragma unroll
    for (int j = 0; j < 8; ++j) {
      float t = s_acc[kk][j];
      t += __shfl_xor(t, 1);
      t += __shfl_xor(t, 2);
      t += __shfl_xor(t, 4);
      t += __shfl_xor(t, 8);
      s_acc[kk][j] = t;
    }
  if (l15 == 0) {
    #pragma unroll
    for (int kk = 0; kk < 4; ++kk)
      #pragma unroll
      for (int j = 0; j < 8; ++j)
        s_fin[32 * kk + 8 * q + j] = s_acc[kk][j];
  }
  __syncthreads();

  // softmax over m' for each e-column (e = 16nt + l15); out += s[e] * alpha
  float o[8][4];
  #pragma unroll
  for (int mt = 0; mt < 8; ++mt)
    #pragma unroll
    for (int r = 0; r < 4; ++r) o[mt][r] = 0.0f;

  #pragma unroll
  for (int nt = 0; nt < 8; ++nt) {
    float mx = -3.0e38f;
    #pragma unroll
    for (int mt = 0; mt < 8; ++mt)
      #pragma unroll
      for (int r = 0; r < 4; ++r) mx = fmaxf(mx, acc[mt][nt][r]);
    mx = fmaxf(mx, __shfl_xor(mx, 16));
    mx = fmaxf(mx, __shfl_xor(mx, 32));

    float sum = 0.0f;
    #pragma unroll
    for (int mt = 0; mt < 8; ++mt)
      #pragma unroll
      for (int r = 0; r < 4; ++r) {
        float p = __expf(acc[mt][nt][r] - mx);
        acc[mt][nt][r] = p;
        sum += p;
      }
    sum += __shfl_xor(sum, 16);
    sum += __shfl_xor(sum, 32);

    const float wrow = s_fin[16 * nt + l15] * __builtin_amdgcn_rcpf(sum);
    #pragma unroll
    for (int mt = 0; mt < 8; ++mt)
      #pragma unroll
      for (int r = 0; r < 4; ++r)
        o[mt][r] = fmaf(acc[mt][nt][r], wrow, o[mt][r]);
  }

  // reduce over e-columns held by the 16 l15-lanes; store from l15==0
  #pragma unroll
  for (int mt = 0; mt < 8; ++mt)
    #pragma unroll
    for (int r = 0; r < 4; ++r) {
      float t = o[mt][r];
      t += __shfl_xor(t, 1);
      t += __shfl_xor(t, 2);
      t += __shfl_xor(t, 4);
      t += __shfl_xor(t, 8);
      o[mt][r] = t;
    }
  if (l15 == 0) {
    #pragma unroll
    for (int mt = 0; mt < 8; ++mt)
      #pragma unroll
      for (int r = 0; r < 4; ++r)
        outp[(size_t)bi * E_DIM + 16 * mt + 4 * q + r] = o[mt][r];
  }
}

extern "C" void kernel_launch(void* const* d_in, const int* in_sizes, int n_in,
                              void* d_out, int out_size, void* d_ws, size_t ws_size,
                              hipStream_t stream) {
  const float* mp = (const float*)d_in[0];  // m (B,T,E) fp32
  const float* vp = (const float*)d_in[1];  // v (T,E)   fp32 (B==T)
  const float* Wp = (const float*)d_in[2];  // W (B,E,E) fp32
  const float* bp = (const float*)d_in[3];  // b (B,E)   fp32 (time-broadcast)
  float* outp = (float*)d_out;              // out (B,E) fp32

  const size_t vt_bytes = (size_t)E_DIM * T_DIM * sizeof(_Float16);  // 256 KB
  if (ws_size >= vt_bytes) {
    _Float16* vT = (_Float16*)d_ws;
    v_transpose_kernel<<<dim3(E_DIM), dim3(256), 0, stream>>>(vp, vT);
    attn_mv_main<true><<<dim3(B_DIM), dim3(64), 0, stream>>>(mp, vp, vT, Wp, bp, outp);
  } else {
    attn_mv_main<false><<<dim3(B_DIM), dim3(64), 0, stream>>>(mp, vp, nullptr, Wp, bp, outp);
  }
}

// Round 4
// 999.273 us; speedup vs baseline: 1.6354x; 1.6354x over previous
//
#include <hip/hip_runtime.h>
#include <cstddef>

typedef _Float16 h8 __attribute__((ext_vector_type(8)));
typedef _Float16 h4 __attribute__((ext_vector_type(4)));
typedef float f32x4 __attribute__((ext_vector_type(4)));

#define B_DIM 1024
#define T_DIM 1024
#define E_DIM 128

// tanh(x) = 1 - 2/(exp(2x)+1); exact at saturation.
__device__ __forceinline__ float tanh_fast(float x) {
  float ex = __expf(2.0f * x);
  return 1.0f - 2.0f * __builtin_amdgcn_rcpf(ex + 1.0f);
}

// ws pre-kernel: vT[e][t] = v[t][e], bT[f][t] = b[t][f]  (f16, 256 KB each).
__global__ void transpose_vb_kernel(const float* __restrict__ vp,
                                    const float* __restrict__ bp,
                                    _Float16* __restrict__ vT,
                                    _Float16* __restrict__ bT) {
  const int e = blockIdx.x;
  for (int t = threadIdx.x; t < T_DIM; t += 256) {
    vT[e * T_DIM + t] = (_Float16)vp[t * E_DIM + e];
    bT[e * T_DIM + t] = (_Float16)bp[t * E_DIM + e];
  }
}

// One block (4 waves) per batch. Wave wv owns f-columns [32wv,32wv+32) of u and
// m'-rows [32wv,32wv+32) of pre^T. W_b columns live in 32 VGPRs/lane (no W LDS).
// Per 64-row t-tile: m staged f16 in LDS (XOR-swizzled on row&15, double-buffered,
// 1 barrier/tile); step1 u = tanh(m@W + b) (16x16x32 MFMA, K=128); step1's
// C-layout regs ARE the A-operand of u^T for K=16 MFMA -> step2 pre^T += u^T @ v
// with no LDS round-trip. Epilogue: cross-wave softmax over m' + out = s^T alpha.
template <bool USE_WS>
__global__ __launch_bounds__(256, 2)
void attn_mv_main(const float* __restrict__ mp, const float* __restrict__ vp,
                  const float* __restrict__ Wp, const float* __restrict__ bp,
                  const _Float16* __restrict__ vTp, const _Float16* __restrict__ bTp,
                  float* __restrict__ outp)
{
  const int bi   = blockIdx.x;
  const int tid  = threadIdx.x;
  const int wv   = tid >> 6;
  const int lane = tid & 63;
  const int l15  = lane & 15;
  const int q    = lane >> 4;
  const int h    = lane >> 5;          // staging row-half (0/1)
  const int cst  = (lane & 31) >> 1;   // staging chunk 0..15 (8 f16 per chunk)
  const int wipk = 4 * (lane & 1);     // within-chunk f16 offset (0 or 4)

  __shared__ _Float16 mS[2 * 64 * 128];   // 32 KB, swizzle: chunk' = chunk ^ (row&15)
  __shared__ float s_part[8 * 128];       // colsum partials
  __shared__ float smax[4 * 128];
  __shared__ float ssum[4 * 128];
  __shared__ float s_fin[128];

  // ---- W_b columns f in [32wv,32wv+32) as f16 B-frags in regs (one-time gather)
  const float* Wb = Wp + (size_t)bi * (E_DIM * E_DIM);
  h8 Wr[2][4];
  #pragma unroll
  for (int ft = 0; ft < 2; ++ft)
    #pragma unroll
    for (int kk = 0; kk < 4; ++kk)
      #pragma unroll
      for (int j = 0; j < 8; ++j)
        Wr[ft][kk][j] = (_Float16)Wb[(32 * kk + 8 * q + j) * E_DIM + 32 * wv + 16 * ft + l15];

  f32x4 acc[2][8];   // pre^T tiles: m' = 32wv+16mta+4q+r, e = 16et+l15
  #pragma unroll
  for (int mta = 0; mta < 2; ++mta)
    #pragma unroll
    for (int et = 0; et < 8; ++et)
      #pragma unroll
      for (int r = 0; r < 4; ++r) acc[mta][et][r] = 0.0f;

  float s_acc[4] = {0.0f, 0.0f, 0.0f, 0.0f};  // cols 4*(lane&31)+j, fp32 exact

  // wave wv owns tile rows [16wv, 16wv+16): global row = t0 + 16wv + 2rr + h
  const float* mw = mp + (size_t)bi * T_DIM * E_DIM + (16 * wv) * E_DIM;

  // ---- prologue: stage tile 0 into buffer 0
  f32x4 mraw[8];
  #pragma unroll
  for (int rr = 0; rr < 8; ++rr)
    mraw[rr] = *(const f32x4*)&mw[(size_t)(2 * rr + h) * E_DIM + 4 * (lane & 31)];
  #pragma unroll
  for (int rr = 0; rr < 8; ++rr) {
    const int r16 = 2 * rr + h;           // row mod 16
    const int row = 16 * wv + r16;        // slab row 0..63
    h4 c4;
    #pragma unroll
    for (int j = 0; j < 4; ++j) { s_acc[j] += mraw[rr][j]; c4[j] = (_Float16)mraw[rr][j]; }
    *(h4*)&mS[row * 128 + ((cst ^ r16) * 8) + wipk] = c4;
  }

  #pragma unroll 1
  for (int i = 0; i < 16; ++i) {
    const int t0  = i * 64;
    const int cur = i & 1;
    const int nxt = (i + 1) & 1;
    __syncthreads();   // slab[cur] visible; slab[nxt] free (WAR safe)

    // ---- prefetch next tile's m rows into regs (consumed at loop bottom)
    if (i < 15) {
      const float* mwn = mw + (size_t)(t0 + 64) * E_DIM;
      #pragma unroll
      for (int rr = 0; rr < 8; ++rr)
        mraw[rr] = *(const f32x4*)&mwn[(size_t)(2 * rr + h) * E_DIM + 4 * (lane & 31)];
    }

    // ---- v B-frags (kk3=0) + bias frags, f16 from ws (L2-hot)
    h4 vb[2][8];
    h4 bt[4][2];
    if (USE_WS) {
      #pragma unroll
      for (int et = 0; et < 8; ++et)
        vb[0][et] = *(const h4*)&vTp[(16 * et + l15) * T_DIM + t0 + 4 * q];
      #pragma unroll
      for (int mtt = 0; mtt < 4; ++mtt)
        #pragma unroll
        for (int ft = 0; ft < 2; ++ft)
          bt[mtt][ft] = *(const h4*)&bTp[(32 * wv + 16 * ft + l15) * T_DIM + t0 + 16 * mtt + 4 * q];
    } else {
      #pragma unroll
      for (int et = 0; et < 8; ++et)
        #pragma unroll
        for (int j = 0; j < 4; ++j)
          vb[0][et][j] = (_Float16)vp[(t0 + 4 * q + j) * E_DIM + 16 * et + l15];
      #pragma unroll
      for (int mtt = 0; mtt < 4; ++mtt)
        #pragma unroll
        for (int ft = 0; ft < 2; ++ft)
          #pragma unroll
          for (int r = 0; r < 4; ++r)
            bt[mtt][ft][r] = (_Float16)bp[(t0 + 16 * mtt + 4 * q + r) * E_DIM + 32 * wv + 16 * ft + l15];
    }

    // ---- step1: u[t][f] tiles, K=128 over e. A from swizzled slab, B from regs.
    f32x4 uacc[4][2];
    #pragma unroll
    for (int mtt = 0; mtt < 4; ++mtt)
      #pragma unroll
      for (int ft = 0; ft < 2; ++ft)
        #pragma unroll
        for (int r = 0; r < 4; ++r) uacc[mtt][ft][r] = 0.0f;

    #pragma unroll
    for (int kk = 0; kk < 4; ++kk) {
      const int coff = ((4 * kk + q) ^ l15) * 8;   // read row&15 == l15
      #pragma unroll
      for (int mtt = 0; mtt < 4; ++mtt) {
        h8 a = *(const h8*)&mS[cur * 8192 + (16 * mtt + l15) * 128 + coff];
        uacc[mtt][0] = __builtin_amdgcn_mfma_f32_16x16x32_f16(a, Wr[0][kk], uacc[mtt][0], 0, 0, 0);
        uacc[mtt][1] = __builtin_amdgcn_mfma_f32_16x16x32_f16(a, Wr[1][kk], uacc[mtt][1], 0, 0, 0);
      }
    }

    // ---- tanh + bias + pack: C-layout (t=16mtt+4q+r, f=..+l15) IS A-layout of u^T
    h4 pk[4][2];
    #pragma unroll
    for (int mtt = 0; mtt < 4; ++mtt)
      #pragma unroll
      for (int ft = 0; ft < 2; ++ft)
        #pragma unroll
        for (int r = 0; r < 4; ++r)
          pk[mtt][ft][r] = (_Float16)tanh_fast(uacc[mtt][ft][r] + (float)bt[mtt][ft][r]);

    // ---- step2: pre^T += u^T @ v, K=16 per kk3, rolling v-frag buffer
    #pragma unroll
    for (int kk3 = 0; kk3 < 4; ++kk3) {
      if (kk3 < 3) {
        const int nb = (kk3 + 1) & 1;
        if (USE_WS) {
          #pragma unroll
          for (int et = 0; et < 8; ++et)
            vb[nb][et] = *(const h4*)&vTp[(16 * et + l15) * T_DIM + t0 + 16 * (kk3 + 1) + 4 * q];
        } else {
          #pragma unroll
          for (int et = 0; et < 8; ++et)
            #pragma unroll
            for (int j = 0; j < 4; ++j)
              vb[nb][et][j] = (_Float16)vp[(t0 + 16 * (kk3 + 1) + 4 * q + j) * E_DIM + 16 * et + l15];
        }
      }
      const int cb = kk3 & 1;
      #pragma unroll
      for (int et = 0; et < 8; ++et) {
        acc[0][et] = __builtin_amdgcn_mfma_f32_16x16x16f16(pk[kk3][0], vb[cb][et], acc[0][et], 0, 0, 0);
        acc[1][et] = __builtin_amdgcn_mfma_f32_16x16x16f16(pk[kk3][1], vb[cb][et], acc[1][et], 0, 0, 0);
      }
    }

    // ---- colsum + cvt + stage next tile into slab[nxt]
    if (i < 15) {
      #pragma unroll
      for (int rr = 0; rr < 8; ++rr) {
        const int r16 = 2 * rr + h;
        const int row = 16 * wv + r16;
        h4 c4;
        #pragma unroll
        for (int j = 0; j < 4; ++j) { s_acc[j] += mraw[rr][j]; c4[j] = (_Float16)mraw[rr][j]; }
        *(h4*)&mS[nxt * 8192 + row * 128 + ((cst ^ r16) * 8) + wipk] = c4;
      }
    }
  }

  // ==== epilogue ====
  // colsum partials + per-wave softmax maxima to LDS
  const int p8 = wv * 2 + h;
  #pragma unroll
  for (int j = 0; j < 4; ++j) s_part[p8 * 128 + 4 * (lane & 31) + j] = s_acc[j];

  float gmx[8];
  #pragma unroll
  for (int et = 0; et < 8; ++et) {
    float mx = -3.0e38f;
    #pragma unroll
    for (int mta = 0; mta < 2; ++mta)
      #pragma unroll
      for (int r = 0; r < 4; ++r) mx = fmaxf(mx, acc[mta][et][r]);
    mx = fmaxf(mx, __shfl_xor(mx, 16));
    mx = fmaxf(mx, __shfl_xor(mx, 32));
    if (q == 0) smax[wv * 128 + 16 * et + l15] = mx;
  }
  __syncthreads();

  if (tid < 128) {
    float s = 0.0f;
    #pragma unroll
    for (int p = 0; p < 8; ++p) s += s_part[p * 128 + tid];
    s_fin[tid] = s;
  }

  #pragma unroll
  for (int et = 0; et < 8; ++et) {
    const int e = 16 * et + l15;
    gmx[et] = fmaxf(fmaxf(smax[e], smax[128 + e]), fmaxf(smax[256 + e], smax[384 + e]));
    float sum = 0.0f;
    #pragma unroll
    for (int mta = 0; mta < 2; ++mta)
      #pragma unroll
      for (int r = 0; r < 4; ++r) {
        float p = __expf(acc[mta][et][r] - gmx[et]);
        acc[mta][et][r] = p;
        sum += p;
      }
    sum += __shfl_xor(sum, 16);
    sum += __shfl_xor(sum, 32);
    if (q == 0) ssum[wv * 128 + e] = sum;
  }
  __syncthreads();

  float o[2][4];
  #pragma unroll
  for (int mta = 0; mta < 2; ++mta)
    #pragma unroll
    for (int r = 0; r < 4; ++r) o[mta][r] = 0.0f;

  #pragma unroll
  for (int et = 0; et < 8; ++et) {
    const int e = 16 * et + l15;
    const float gs = ssum[e] + ssum[128 + e] + ssum[256 + e] + ssum[384 + e];
    const float wr = s_fin[e] * __builtin_amdgcn_rcpf(gs);
    #pragma unroll
    for (int mta = 0; mta < 2; ++mta)
      #pragma unroll
      for (int r = 0; r < 4; ++r)
        o[mta][r] = fmaf(acc[mta][et][r], wr, o[mta][r]);
  }
  #pragma unroll
  for (int mta = 0; mta < 2; ++mta)
    #pragma unroll
    for (int r = 0; r < 4; ++r) {
      float t = o[mta][r];
      t += __shfl_xor(t, 1);
      t += __shfl_xor(t, 2);
      t += __shfl_xor(t, 4);
      t += __shfl_xor(t, 8);
      o[mta][r] = t;
    }
  if (l15 == 0) {
    #pragma unroll
    for (int mta = 0; mta < 2; ++mta)
      #pragma unroll
      for (int r = 0; r < 4; ++r)
        outp[(size_t)bi * E_DIM + 32 * wv + 16 * mta + 4 * q + r] = o[mta][r];
  }
}

extern "C" void kernel_launch(void* const* d_in, const int* in_sizes, int n_in,
                              void* d_out, int out_size, void* d_ws, size_t ws_size,
                              hipStream_t stream) {
  const float* mp = (const float*)d_in[0];
  const float* vp = (const float*)d_in[1];
  const float* Wp = (const float*)d_in[2];
  const float* bp = (const float*)d_in[3];
  float* outp = (float*)d_out;

  const size_t need = 2 * (size_t)E_DIM * T_DIM * sizeof(_Float16);  // 512 KB
  if (ws_size >= need) {
    _Float16* vT = (_Float16*)d_ws;
    _Float16* bT = vT + (size_t)E_DIM * T_DIM;
    transpose_vb_kernel<<<dim3(E_DIM), dim3(256), 0, stream>>>(vp, bp, vT, bT);
    attn_mv_main<true><<<dim3(B_DIM), dim3(256), 0, stream>>>(mp, vp, Wp, bp, vT, bT, outp);
  } else {
    attn_mv_main<false><<<dim3(B_DIM), dim3(256), 0, stream>>>(mp, vp, Wp, bp, nullptr, nullptr, outp);
  }
}